// Round 2
// baseline (48139.902 us; speedup 1.0000x reference)
//
#include <hip/hip_runtime.h>
#include <hip/hip_cooperative_groups.h>

namespace cg = cooperative_groups;

typedef __attribute__((ext_vector_type(8))) short short8;
typedef __attribute__((ext_vector_type(4))) float floatx4;

#define SEQ 512
#define BS  64
#define HID 1024
#define G4  4096
#define NBLK 128
#define UPB 8    // hidden units per block

__device__ __forceinline__ unsigned short f2b(float f) {
  union { float f; unsigned u; } v; v.f = f;
  return (unsigned short)((v.u + 0x7FFFu + ((v.u >> 16) & 1u)) >> 16);
}
__device__ __forceinline__ float b2f(unsigned short s) {
  union { unsigned u; float f; } v; v.u = ((unsigned)s) << 16;
  return v.f;
}

__device__ __forceinline__ void gload_lds16(const void* g, void* l) {
  __builtin_amdgcn_global_load_lds(
      (const __attribute__((address_space(1))) unsigned int*)g,
      (__attribute__((address_space(3))) unsigned int*)l,
      16, 0, 0);
}

// ---- weight transpose+convert: W[1024][4096] f32 -> WT[4096][1024] bf16
__global__ void wtrans(const float* __restrict__ W, short* __restrict__ WT) {
  __shared__ float tile[32][33];
  const int tx = threadIdx.x, ty = threadIdx.y;
  const int n0 = blockIdx.x << 5, k0 = blockIdx.y << 5;
#pragma unroll
  for (int i = 0; i < 32; i += 8)
    tile[ty + i][tx] = W[(size_t)(k0 + ty + i) * G4 + n0 + tx];
  __syncthreads();
#pragma unroll
  for (int i = 0; i < 32; i += 8)
    WT[(size_t)(n0 + ty + i) * 1024 + k0 + tx] = (short)f2b(tile[tx][ty + i]);
}

// ---- projection GEMM: out[M][4096] = A[M][1024](f32) @ WT^T + bias
__global__ __launch_bounds__(256)
void gemm_xw(const float* __restrict__ A, const short* __restrict__ BT,
             const float* __restrict__ bias, void* __restrict__ xw, int xw_f32) {
  __shared__ short Al[128 * 40];
  __shared__ short Bl[128 * 40];
  const int tid = threadIdx.x;
  const int wave = tid >> 6, lane = tid & 63;
  const int lr = lane & 15, lh = lane >> 4;
  const int wm = wave >> 1, wn = wave & 1;
  const int m0 = blockIdx.y << 7;
  const int n0 = blockIdx.x << 7;
  const int arow = tid >> 1, akc = tid & 1;

  const float* aptr = A + (size_t)(m0 + arow) * 1024 + akc * 16;
  const short* bptr = BT + (size_t)(n0 + arow) * 1024 + akc * 16;

  floatx4 acc[4][4] = {};
  floatx4 fa[4];
  short8 pb0, pb1;
#pragma unroll
  for (int j = 0; j < 4; ++j) fa[j] = *(const floatx4*)(aptr + 4 * j);
  pb0 = *(const short8*)(bptr);
  pb1 = *(const short8*)(bptr + 8);

  for (int it = 0; it < 32; ++it) {
    __syncthreads();
    unsigned short us[16];
#pragma unroll
    for (int j = 0; j < 4; ++j)
#pragma unroll
      for (int e = 0; e < 4; ++e) us[4 * j + e] = f2b(fa[j][e]);
    short8 s0, s1;
#pragma unroll
    for (int e = 0; e < 8; ++e) { s0[e] = (short)us[e]; s1[e] = (short)us[8 + e]; }
    *(short8*)&Al[arow * 40 + akc * 16 + 0] = s0;
    *(short8*)&Al[arow * 40 + akc * 16 + 8] = s1;
    *(short8*)&Bl[arow * 40 + akc * 16 + 0] = pb0;
    *(short8*)&Bl[arow * 40 + akc * 16 + 8] = pb1;
    __syncthreads();
    if (it < 31) {
      const int k0 = (it + 1) << 5;
#pragma unroll
      for (int j = 0; j < 4; ++j) fa[j] = *(const floatx4*)(aptr + k0 + 4 * j);
      pb0 = *(const short8*)(bptr + k0);
      pb1 = *(const short8*)(bptr + k0 + 8);
    }
    short8 af[4], bf[4];
#pragma unroll
    for (int mt = 0; mt < 4; ++mt) af[mt] = *(const short8*)&Al[(wm * 64 + mt * 16 + lr) * 40 + lh * 8];
#pragma unroll
    for (int nt = 0; nt < 4; ++nt) bf[nt] = *(const short8*)&Bl[(wn * 64 + nt * 16 + lr) * 40 + lh * 8];
#pragma unroll
    for (int mt = 0; mt < 4; ++mt)
#pragma unroll
      for (int nt = 0; nt < 4; ++nt)
        acc[mt][nt] = __builtin_amdgcn_mfma_f32_16x16x32_bf16(af[mt], bf[nt], acc[mt][nt], 0, 0, 0);
  }
#pragma unroll
  for (int nt = 0; nt < 4; ++nt) {
    const int gcol = n0 + wn * 64 + nt * 16 + lr;
    const float bv = bias[gcol];
#pragma unroll
    for (int mt = 0; mt < 4; ++mt)
#pragma unroll
      for (int r = 0; r < 4; ++r) {
        const int grow = m0 + wm * 64 + mt * 16 + lh * 4 + r;
        const float v = acc[mt][nt][r] + bv;
        if (xw_f32) ((float*)xw)[(size_t)grow * G4 + gcol] = v;
        else        ((unsigned short*)xw)[(size_t)grow * G4 + gcol] = f2b(v);
      }
  }
}

struct Scan2Args {
  const void* xw;          // input projection for this chunk (f32 or bf16)
  const short* wt_hi;      // WT of W_hi [4096][1024] bf16
  unsigned short* hbuf;    // [2][64*1024] bf16 ping-pong
  float* cbuf;             // [64*1024] f32 persistent cell state
  float* hs;               // hs output f32 [512][64][1024]
  float* h_final;
  float* c_final;
  int t0, t1, wr_final;
};

// 128 blocks x 512 threads. Block owns units [8b,8b+8) => 32 gate cols.
// W_hi fragments register-resident (128 VGPR); h_t staged to 128KB LDS/step.
template<int XW_F32>
__global__ __launch_bounds__(512, 1)
void lstm_scan2(Scan2Args p) {
  __shared__ char smem[131072];          // h tile [64][1024] bf16, XOR-swizzled
  float* gsm = (float*)smem;             // overlay after K-loop: gates [64][33]
  const int tid = threadIdx.x;
  const int wave = tid >> 6, lane = tid & 63;
  const int lr = lane & 15, lh = lane >> 4;
  const int wm = wave >> 1;              // M tile 0..3 (16 batch rows each)
  const int wn = wave & 1;               // N half 0..1 (16 cols each)
  const int blk = blockIdx.x;
  const int nloc = wn * 16 + lr;                               // 0..31
  const int gcol = ((nloc >> 3) << 10) + blk * UPB + (nloc & 7);
  cg::grid_group grid = cg::this_grid();

  // ---- preload B fragments (W_hi) into registers: 32 x short8 = 128 VGPR
  short8 breg[32];
  {
    const short* wp = p.wt_hi + (size_t)gcol * HID + lh * 8;
#pragma unroll
    for (int kk = 0; kk < 32; ++kk) breg[kk] = *(const short8*)(wp + (kk << 5));
  }

  // ---- persistent cell state: 1 element per thread
  const int ub = tid >> 3, uu = tid & 7;
  const int ci = (ub << 10) + blk * UPB + uu;
  float creg = p.cbuf[ci];

  const int arow = (wm << 4) + lr;       // A-frag row for this lane
  const int asw = lr & 7;                // read-side XOR swizzle

  for (int t = p.t0; t < p.t1; ++t) {
    const unsigned short* hb = p.hbuf + (size_t)(t & 1) * (BS * HID);
    unsigned short* hw = p.hbuf + (size_t)((t + 1) & 1) * (BS * HID);

    // ---- stage h_t -> LDS: 16 gload_lds/wave, linear dest, inv-swz source
#pragma unroll
    for (int j = 0; j < 16; ++j) {
      const int i = (wave << 4) + j;     // 0..127 (1KB LDS spans)
      const int row = i >> 1, half = i & 1;
      const int chunk = ((half << 6) + lane) ^ (row & 7);
      gload_lds16(hb + row * HID + (chunk << 3), smem + (i << 10));
    }
    asm volatile("s_waitcnt vmcnt(0)" ::: "memory");
    __builtin_amdgcn_s_barrier();

    // ---- xw loads issued here: hidden under the K loop
    float xv[4];
#pragma unroll
    for (int r = 0; r < 4; ++r) {
      const size_t rowi = (size_t)(t - p.t0) * BS + (wm << 4) + (lh << 2) + r;
      if (XW_F32) xv[r] = ((const float*)p.xw)[rowi * G4 + gcol];
      else        xv[r] = b2f(((const unsigned short*)p.xw)[rowi * G4 + gcol]);
    }

    // ---- K loop: 32 x (ds_read_b128 + MFMA), B from registers
    floatx4 acc = {0.f, 0.f, 0.f, 0.f};
#pragma unroll
    for (int kk = 0; kk < 32; ++kk) {
      const int off = (arow << 11) + (((((kk << 2) + lh)) ^ asw) << 4);
      const short8 afr = *(const short8*)(smem + off);
      acc = __builtin_amdgcn_mfma_f32_16x16x32_bf16(afr, breg[kk], acc, 0, 0, 0);
    }
    __syncthreads();

    // ---- gate pre-activations to LDS overlay
#pragma unroll
    for (int r = 0; r < 4; ++r) {
      const int b = (wm << 4) + (lh << 2) + r;
      gsm[b * 33 + nloc] = acc[r] + xv[r];
    }
    __syncthreads();

    // ---- elementwise update: 1 (batch,unit) per thread
    {
      const float ig = gsm[ub * 33 + uu];
      const float fg = gsm[ub * 33 + 8 + uu];
      const float gg = gsm[ub * 33 + 16 + uu];
      const float og = gsm[ub * 33 + 24 + uu];
      const float iv = 1.f / (1.f + __expf(-ig));
      const float fv = 1.f / (1.f + __expf(-fg));
      const float gv = tanhf(gg);
      const float ov = 1.f / (1.f + __expf(-og));
      const float cn = fv * creg + iv * gv;
      creg = cn;
      const float hv = ov * tanhf(cn);
      hw[ci] = f2b(hv);
      p.hs[((size_t)t * BS + ub) * HID + blk * UPB + uu] = hv;
      if (p.wr_final && t == SEQ - 1) { p.h_final[ci] = hv; p.c_final[ci] = cn; }
    }
    __threadfence();
    grid.sync();
  }
  p.cbuf[ci] = creg;
}

extern "C" void kernel_launch(void* const* d_in, const int* in_sizes, int n_in,
                              void* d_out, int out_size, void* d_ws, size_t ws_size,
                              hipStream_t stream) {
  const float* x    = (const float*)d_in[0];
  const float* Wii0 = (const float*)d_in[1];
  const float* Wii  = (const float*)d_in[2];
  const float* Whi  = (const float*)d_in[3];
  const float* bias = (const float*)d_in[4];
  float* out  = (float*)d_out;
  float* hs   = out;
  float* hfin = out + (size_t)SEQ * BS * HID;
  float* cfin = hfin + BS * HID;

  char* ws = (char*)d_ws;
  short* WT0 = (short*)ws;
  short* WT1 = WT0 + (size_t)G4 * 1024;
  short* WTh = WT1 + (size_t)G4 * 1024;
  unsigned short* hbuf = (unsigned short*)(WTh + (size_t)G4 * 1024);
  float* cbuf = (float*)(hbuf + 2 * BS * HID);
  char* tail = (char*)(cbuf + BS * HID);
  const size_t head = (size_t)(tail - ws);
  const size_t avail = (ws_size > head) ? ws_size - head : 0;

  int chunk, xwF32;
  if      (avail >= (size_t)SEQ * BS * G4 * 4) { chunk = SEQ; xwF32 = 1; }
  else if (avail >= (size_t)SEQ * BS * G4 * 2) { chunk = SEQ; xwF32 = 0; }
  else if (avail >= (size_t)64  * BS * G4 * 4) { chunk = 64;  xwF32 = 1; }
  else if (avail >= (size_t)64  * BS * G4 * 2) { chunk = 64;  xwF32 = 0; }
  else if (avail >= (size_t)16  * BS * G4 * 2) { chunk = 16;  xwF32 = 0; }
  else                                         { chunk = 4;   xwF32 = 0; }

  wtrans<<<dim3(128, 32), dim3(32, 8), 0, stream>>>(Wii0, WT0);
  wtrans<<<dim3(128, 32), dim3(32, 8), 0, stream>>>(Wii, WT1);
  wtrans<<<dim3(128, 32), dim3(32, 8), 0, stream>>>(Whi, WTh);

  const void* scan_fn = xwF32 ? reinterpret_cast<const void*>(&lstm_scan2<1>)
                              : reinterpret_cast<const void*>(&lstm_scan2<0>);

  for (int layer = 0; layer < 2; ++layer) {
    hipMemsetAsync(hbuf, 0, 2 * BS * HID * sizeof(unsigned short), stream);
    hipMemsetAsync(cbuf, 0, BS * HID * sizeof(float), stream);

    for (int t0 = 0; t0 < SEQ; t0 += chunk) {
      const float* Ain = (layer ? hs : x) + (size_t)t0 * BS * 1024;
      gemm_xw<<<dim3(32, chunk * BS / 128), dim3(256), 0, stream>>>(
          Ain, layer ? WT1 : WT0, bias, (void*)tail, xwF32);

      Scan2Args sa;
      sa.xw = (const void*)tail;
      sa.wt_hi = WTh;
      sa.hbuf = hbuf;
      sa.cbuf = cbuf;
      sa.hs = hs;
      sa.h_final = layer ? hfin : nullptr;
      sa.c_final = layer ? cfin : nullptr;
      sa.t0 = t0;
      sa.t1 = t0 + chunk;
      sa.wr_final = layer;
      void* args[] = { &sa };
      hipLaunchCooperativeKernel(scan_fn, dim3(NBLK), dim3(512), args, 0u, stream);
    }
  }
}